// Round 9
// baseline (283.902 us; speedup 1.0000x reference)
//
#include <hip/hip_runtime.h>
#include <hip/hip_bf16.h>
#include <float.h>

// Problem constants
#define NPIX   32768      // B*H*W
#define CDIM   128
#define KCB    8192
#define EPS_STOP 0.30f    // mask quant (0.031) + f16-dot error bound
#define TAUF   0.012f     // exact fp32 gap guard -> fp64 arbitration
#define RCAP   8192
#define RCAPA  2048

typedef _Float16 f16x8 __attribute__((ext_vector_type(8)));
typedef float    f32x16 __attribute__((ext_vector_type(16)));

// ws layout (bytes)
#define WS_EMBFH   0           // 2,359,296
#define WS_E2      2359296     // 32,768 (unused now)
#define WS_ZWS     2392064     // 16,777,216
#define WS_CAND    19169280    // 1,048,576 (unused now)
#define WS_IDX     20217856    // 131,072
#define WS_RLISTA  20348928    // 32,768 (cap 2048 used)
#define WS_RLISTB  20381696    // 131,072 (8192 * int4)
#define WS_SCAND   20512768    // 524,288 (2048*32 double)
#define WS_SCANI   21037056    // 262,144 (2048*32 int)
#define WS_COUNTS  21299200    // 32,768
#define WS_LOSS    21331968    // 4
#define WS_RCNTA   21331972    // 4
#define WS_RCNTB   21331976    // 4
#define WS_ZERO_OFF 21299200
#define WS_ZERO_LEN 32780      // 8195 ints

// d_out layout (f32): [0]=loss, [1..4194304]=out BCHW, [4194305]=perplexity, [4194306..]=idx
#define OUT_OFF_OUT  1
#define OUT_OFF_PERP 4194305
#define OUT_OFF_IDX  4194306

__device__ __forceinline__ float min3f(float a, float b, float c) {
    return fminf(fminf(a, b), c);   // -> v_min3_f32
}

__device__ __forceinline__ void ins6(float f, float v[6]) {
    float a = fmaxf(v[0], f); v[0] = fminf(v[0], f);
    float b = fmaxf(v[1], a); v[1] = fminf(v[1], a);
    a = fmaxf(v[2], b); v[2] = fminf(v[2], b);
    b = fmaxf(v[3], a); v[3] = fminf(v[3], a);
    a = fmaxf(v[4], b); v[4] = fminf(v[4], b);
    v[5] = fminf(v[5], a);
}

__device__ __forceinline__ float packmin(float m, uint32_t id) {
    return __uint_as_float((__float_as_uint(m) & 0xFFFFFE00u) | id);
}

// ---------------- K01: fused e2 + fragment prep + workspace zeroing ----------------
__global__ __launch_bounds__(256) void k_prep2(const float* __restrict__ emb,
                                               _Float16* __restrict__ embFh,
                                               int* __restrict__ zerobuf) {
    const int t = threadIdx.x, w = t >> 6, l = t & 63;
    if (blockIdx.x < 9) {
        int idx0 = blockIdx.x * 1024 + t * 4;
        #pragma unroll
        for (int k = 0; k < 4; ++k)
            if (idx0 + k < 8195) zerobuf[idx0 + k] = 0;
    }
    __shared__ float rs[4][128];
    const int m = blockIdx.x * 4 + w;
    const float2 v = *(const float2*)&emb[(size_t)m * 128 + l * 2];
    rs[w][l * 2] = v.x; rs[w][l * 2 + 1] = v.y;
    float s = v.x * v.x + v.y * v.y;
    #pragma unroll
    for (int o = 32; o; o >>= 1) s += __shfl_down(s, o, 64);
    const float e2v = __shfl(s, 0, 64);

    f16x8 hv;
    #pragma unroll
    for (int j = 0; j < 8; ++j) hv[j] = (_Float16)0.0f;
    if (l < 16) {
        const float* rp = &rs[w][l * 8];
        #pragma unroll
        for (int j = 0; j < 8; ++j) hv[j] = (_Float16)(-2.0f * rp[j]);
    } else if (l == 16) {
        float vv = e2v + 512.0f;
        _Float16 eh = (_Float16)vv;
        hv[0] = eh;
        hv[1] = (_Float16)(vv - (float)eh);
    }
    if (l < 18) {
        const int s_ = l >> 1, h_ = l & 1;
        size_t base = (((size_t)(m >> 5) * 9 + s_) * 64 + (m & 31) + h_ * 32) * 8;
        *(f16x8*)&embFh[base] = hv;
    }
}

// ---------------- K2: fused linear + MFMA + top-6 + IN-KERNEL exact recheck ----------------
// r3 K-loop (proven best, unchanged). NEW: the k_rec early-exit exact fp32 scan is
// fused as an epilogue — 4 passes of the exact k_rec layout (16 lanes/px, same chains,
// same width-16 shfl tree -> bit-identical d1/i1). za/zb come from LDS As (zws re-read
// eliminated), pv/pbase from LDS candL (cand buffer deleted). Co-resident block's
// MFMA phase overlaps this gather-heavy epilogue (m114 MFMA||VALU co-schedule).
__global__ __launch_bounds__(256, 2) void k_main(
    const float* __restrict__ x, const float* __restrict__ Wl, const float* __restrict__ bl,
    const _Float16* __restrict__ embFh, const float* __restrict__ emb,
    float* __restrict__ zws, int* __restrict__ idxws,
    float* __restrict__ out_idxf, float* __restrict__ losssum,
    int* __restrict__ rlistA, int* __restrict__ rcntA,
    int* __restrict__ rlistB, int* __restrict__ rcntB)
{
    __shared__ __align__(16) float As[64 * 132];   // z [p][c], pitch 132 (live to end)
    __shared__ __align__(16) float Xs[64 * 66];    // x staging / merge scratch
    __shared__ float z2p[256];                      // z^2 partials [p][ig] / loss red
    __shared__ float candL[64 * 8];                 // per-pixel v6[0..5], z2

    const int t  = threadIdx.x;
    const int n0 = blockIdx.x * 64;
    const int b  = n0 >> 10;
    const int hw0 = n0 & 1023;

    // ===== Phase 1: z for 64 pixels =====
    {
        const int p = t & 63, ig = t >> 6;
        float accz[32];
        const float4* bl4 = (const float4*)(bl + ig * 32);
        #pragma unroll
        for (int q = 0; q < 8; ++q) {
            float4 v = bl4[q];
            accz[4*q+0] = v.x; accz[4*q+1] = v.y; accz[4*q+2] = v.z; accz[4*q+3] = v.w;
        }
        for (int hf = 0; hf < 2; ++hf) {
            __syncthreads();
            for (int r = 0; r < 16; ++r) {
                int lin = r * 256 + t;
                int cc = lin >> 6, pp = lin & 63;
                Xs[cc * 66 + pp] = x[(size_t)(b * 128 + hf * 64 + cc) * 1024 + hw0 + pp];
            }
            __syncthreads();
            for (int cc4 = 0; cc4 < 16; ++cc4) {
                float xv0 = Xs[(cc4*4+0) * 66 + p];
                float xv1 = Xs[(cc4*4+1) * 66 + p];
                float xv2 = Xs[(cc4*4+2) * 66 + p];
                float xv3 = Xs[(cc4*4+3) * 66 + p];
                #pragma unroll
                for (int ii = 0; ii < 32; ++ii) {
                    const float4 w4 = *(const float4*)&Wl[(size_t)(ig*32+ii) * 128 + hf*64 + cc4*4];
                    float a = accz[ii];
                    a = fmaf(w4.x, xv0, a);
                    a = fmaf(w4.y, xv1, a);
                    a = fmaf(w4.z, xv2, a);
                    a = fmaf(w4.w, xv3, a);
                    accz[ii] = a;
                }
            }
        }
        float ssq = 0.f;
        float4* ao = (float4*)&As[p * 132 + ig * 32];
        float4* zo = (float4*)(zws + (size_t)(n0 + p) * 128 + ig * 32);
        #pragma unroll
        for (int q = 0; q < 8; ++q) {
            float4 v = make_float4(accz[4*q+0], accz[4*q+1], accz[4*q+2], accz[4*q+3]);
            ao[q] = v;
            zo[q] = v;
            ssq = fmaf(v.x, v.x, fmaf(v.y, v.y, fmaf(v.z, v.z, fmaf(v.w, v.w, ssq))));
        }
        z2p[p * 4 + ig] = ssq;
    }
    __syncthreads();

    // ===== Phase 2: B fragments (z f16) + constant fold step =====
    const int l = t & 63, w = t >> 6;
    const int half = l >> 5, pcol = l & 31;
    f16x8 B0[9], B1[9];
    #pragma unroll
    for (int nt = 0; nt < 2; ++nt) {
        int p = nt * 32 + pcol;
        #pragma unroll
        for (int s = 0; s < 8; ++s) {
            const float* zp = &As[p * 132 + s * 16 + half * 8];
            float4 v0 = *(const float4*)zp;
            float4 v1 = *(const float4*)(zp + 4);
            float vals[8] = {v0.x, v0.y, v0.z, v0.w, v1.x, v1.y, v1.z, v1.w};
            f16x8 hh;
            #pragma unroll
            for (int j2 = 0; j2 < 8; ++j2) hh[j2] = (_Float16)vals[j2];
            if (nt == 0) B0[s] = hh; else B1[s] = hh;
        }
    }
    {
        f16x8 b8;
        #pragma unroll
        for (int j2 = 0; j2 < 8; ++j2) b8[j2] = (_Float16)0.0f;
        if (half == 0) { b8[0] = (_Float16)1.0f; b8[1] = (_Float16)1.0f; }
        B0[8] = b8; B1[8] = b8;
    }

    // ===== Phase 3: K-loop, deferred-tail pipeline (UNCHANGED r3) =====
    auto tree16 = [](const f32x16& v) -> float {
        float a = min3f(v[0], v[1], v[2]);
        float bb = min3f(v[3], v[4], v[5]);
        float c = min3f(v[6], v[7], v[8]);
        float d = min3f(v[9], v[10], v[11]);
        float e = min3f(v[12], v[13], v[14]);
        float f = min3f(a, bb, c);
        float g = min3f(d, e, v[15]);
        return fminf(f, g);
    };

    float gv[6] = {3e38f, 3e38f, 3e38f, 3e38f, 3e38f, 3e38f};   // tile0: px = pcol
    float hv[6] = {3e38f, 3e38f, 3e38f, 3e38f, 3e38f, 3e38f};   // tile1: px = 32+pcol
    const f16x8* Ahp = (const f16x8*)embFh;
    f16x8 aE[9], aO[9];
    {
        const f16x8* P = Ahp + (size_t)w * 576 + l;
        #pragma unroll
        for (int s = 0; s < 9; ++s) aE[s] = P[s * 64];
    }
    {
        const f16x8* P = Ahp + (size_t)(w + 4) * 576 + l;
        #pragma unroll
        for (int s = 0; s < 9; ++s) aO[s] = P[s * 64];
    }

    f32x16 e0, e1, o0, o1;
    uint32_t idv = (uint32_t)((w << 1) | half);

    e0 = {}; e1 = {};
    #pragma unroll
    for (int s = 0; s < 9; ++s) {
        e0 = __builtin_amdgcn_mfma_f32_32x32x16_f16(aE[s], B0[s], e0, 0, 0, 0);
        e1 = __builtin_amdgcn_mfma_f32_32x32x16_f16(aE[s], B1[s], e1, 0, 0, 0);
    }

    for (int it = 0; it < 31; ++it) {
        const int g = w + it * 8;
        {
            const f16x8* P = Ahp + (size_t)(g + 8) * 576 + l;
            #pragma unroll
            for (int s = 0; s < 9; ++s) aE[s] = P[s * 64];
        }
        o0 = {}; o1 = {};
        #pragma unroll
        for (int s = 0; s < 9; ++s) {
            o0 = __builtin_amdgcn_mfma_f32_32x32x16_f16(aO[s], B0[s], o0, 0, 0, 0);
            o1 = __builtin_amdgcn_mfma_f32_32x32x16_f16(aO[s], B1[s], o1, 0, 0, 0);
        }
        {
            float m0 = tree16(e0), m1 = tree16(e1);
            ins6(packmin(m0, idv), gv);
            ins6(packmin(m1, idv), hv);
        }
        {
            const f16x8* P = Ahp + (size_t)(g + 12) * 576 + l;
            #pragma unroll
            for (int s = 0; s < 9; ++s) aO[s] = P[s * 64];
        }
        e0 = {}; e1 = {};
        #pragma unroll
        for (int s = 0; s < 9; ++s) {
            e0 = __builtin_amdgcn_mfma_f32_32x32x16_f16(aE[s], B0[s], e0, 0, 0, 0);
            e1 = __builtin_amdgcn_mfma_f32_32x32x16_f16(aE[s], B1[s], e1, 0, 0, 0);
        }
        {
            float m0 = tree16(o0), m1 = tree16(o1);
            ins6(packmin(m0, idv + 8u), gv);
            ins6(packmin(m1, idv + 8u), hv);
        }
        idv += 16u;
    }
    o0 = {}; o1 = {};
    #pragma unroll
    for (int s = 0; s < 9; ++s) {
        o0 = __builtin_amdgcn_mfma_f32_32x32x16_f16(aO[s], B0[s], o0, 0, 0, 0);
        o1 = __builtin_amdgcn_mfma_f32_32x32x16_f16(aO[s], B1[s], o1, 0, 0, 0);
    }
    {
        float m0 = tree16(e0), m1 = tree16(e1);
        ins6(packmin(m0, idv), gv);
        ins6(packmin(m1, idv), hv);
    }
    {
        float m0 = tree16(o0), m1 = tree16(o1);
        ins6(packmin(m0, idv + 8u), gv);
        ins6(packmin(m1, idv + 8u), hv);
    }

    // ===== Phase 4a: cross-wave merge per pixel -> candL (6 groups + z2) =====
    __syncthreads();
    float* Ms = Xs;   // [64 px][8 slots][6]
    const int slot = (w << 1) | half;
    #pragma unroll
    for (int q = 0; q < 6; ++q) {
        Ms[(pcol * 8 + slot) * 6 + q] = gv[q];
        Ms[((32 + pcol) * 8 + slot) * 6 + q] = hv[q];
    }
    __syncthreads();
    if (t < 64) {
        float v6[6] = {3e38f, 3e38f, 3e38f, 3e38f, 3e38f, 3e38f};
        #pragma unroll
        for (int s = 0; s < 48; ++s) ins6(Ms[t * 48 + s], v6);
        float z2 = z2p[t*4+0] + z2p[t*4+1] + z2p[t*4+2] + z2p[t*4+3];
        #pragma unroll
        for (int q = 0; q < 6; ++q) candL[t * 8 + q] = v6[q];
        candL[t * 8 + 6] = z2;
    }
    __syncthreads();

    // ===== Phase 4b: exact fp32 recheck (k_rec body, 4 passes of 16 pixels) =====
    {
        const int pl = t >> 4, j = t & 15;
        float lossacc = 0.f;
        for (int pass = 0; pass < 4; ++pass) {
            const int px = pass * 16 + pl;
            const int n = n0 + px;
            const float4 za = *(const float4*)&As[px * 132 + j * 8];
            const float4 zb = *(const float4*)&As[px * 132 + j * 8 + 4];
            const float* cl = &candL[px * 8];
            const float pv[6] = {cl[0], cl[1], cl[2], cl[3], cl[4], cl[5]};
            const float pbase = cl[6] - 512.0f;   // d = packed + pbase

            float d1 = 3e38f, d2 = 3e38f; int i1 = 0x7fffffff, i2 = 0x7fffffff;
            bool safe = false;
            float lastgmin = 0.f;
            for (int q = 0; q < 6; ++q) {
                uint32_t bits = __float_as_uint(pv[q]);
                float gmin = __uint_as_float(bits & 0xFFFFFE00u);
                lastgmin = gmin;
                if (gmin >= d1 - pbase + EPS_STOP) { safe = true; break; }
                const int mbase = (int)((bits >> 1) & 255u) * 32 + (int)((bits & 1u) << 2);
                #pragma unroll
                for (int c = 0; c < 16; ++c) {
                    int m = mbase + (c & 3) + 8 * (c >> 2);
                    const float4 ea = *(const float4*)&emb[(size_t)m * 128 + j * 8];
                    const float4 eb = *(const float4*)&emb[(size_t)m * 128 + j * 8 + 4];
                    float da0 = za.x - ea.x, da1 = za.y - ea.y, da2 = za.z - ea.z, da3 = za.w - ea.w;
                    float db0 = zb.x - eb.x, db1 = zb.y - eb.y, db2 = zb.z - eb.z, db3 = zb.w - eb.w;
                    float s0 = da0*da0; s0 = fmaf(da1, da1, s0); s0 = fmaf(da2, da2, s0); s0 = fmaf(da3, da3, s0);
                    float s1 = db0*db0; s1 = fmaf(db1, db1, s1); s1 = fmaf(db2, db2, s1); s1 = fmaf(db3, db3, s1);
                    float s = s0 + s1;
                    s += __shfl_xor(s, 1, 16);
                    s += __shfl_xor(s, 2, 16);
                    s += __shfl_xor(s, 4, 16);
                    s += __shfl_xor(s, 8, 16);
                    if (s < d1 || (s == d1 && m < i1)) { d2 = d1; i2 = i1; d1 = s; i1 = m; }
                    else if (s < d2) { d2 = s; i2 = m; }
                }
            }
            if (!safe && lastgmin >= d1 - pbase + EPS_STOP) safe = true;

            if (j == 0) {
                idxws[n] = i1;
                out_idxf[n] = (float)i1;
                if (!safe) {
                    int s = atomicAdd(rcntA, 1);
                    if (s < RCAPA) rlistA[s] = n;
                } else if ((d2 - d1) < TAUF) {
                    int s = atomicAdd(rcntB, 1);
                    if (s < RCAP) { int4 v4 = make_int4(n, i1, i2, 0); ((int4*)rlistB)[s] = v4; }
                }
                lossacc += d1;
            }
        }
        __syncthreads();
        if (j == 0) z2p[pl] = lossacc;   // z2p dead after 4a
        __syncthreads();
        if (t == 0) {
            float ls = 0.f;
            #pragma unroll
            for (int q = 0; q < 16; ++q) ls += z2p[q];
            atomicAdd(losssum, ls);
        }
    }
}

// ---------------- K4a: parallel full scan for !safe pixels ----------------
__global__ __launch_bounds__(256) void k_scanp(
    const float* __restrict__ zws, const float* __restrict__ emb,
    const int* __restrict__ rcntA, const int* __restrict__ rlistA,
    double* __restrict__ scand, int* __restrict__ scani)
{
    int cnt = *rcntA; if (cnt > RCAPA) cnt = RCAPA;
    const int t = threadIdx.x;
    const int chunk = blockIdx.x & 31;
    const int gi = t >> 4, j = t & 15;
    __shared__ double sd[16];
    __shared__ int si[16];
    for (int e = blockIdx.x >> 5; e < cnt; e += 64) {
        const int n = rlistA[e];
        const float4 za = *(const float4*)&zws[(size_t)n * 128 + j * 8];
        const float4 zb = *(const float4*)&zws[(size_t)n * 128 + j * 8 + 4];
        double best = 1e300; int bi = 0x7fffffff;
        const int kbase = chunk * 256 + gi * 16;
        for (int c = 0; c < 16; ++c) {
            const int m = kbase + c;
            const float4 ea = *(const float4*)&emb[(size_t)m * 128 + j * 8];
            const float4 eb = *(const float4*)&emb[(size_t)m * 128 + j * 8 + 4];
            double sa = 0.0, sb = 0.0, d;
            d = (double)za.x - (double)ea.x; sa += d * d;
            d = (double)za.y - (double)ea.y; sa += d * d;
            d = (double)za.z - (double)ea.z; sa += d * d;
            d = (double)za.w - (double)ea.w; sa += d * d;
            d = (double)zb.x - (double)eb.x; sb += d * d;
            d = (double)zb.y - (double)eb.y; sb += d * d;
            d = (double)zb.z - (double)eb.z; sb += d * d;
            d = (double)zb.w - (double)eb.w; sb += d * d;
            double s = sa + sb;
            s += __shfl_xor(s, 1, 16);
            s += __shfl_xor(s, 2, 16);
            s += __shfl_xor(s, 4, 16);
            s += __shfl_xor(s, 8, 16);
            if (s < best) { best = s; bi = m; }   // m strictly increasing -> first-index
        }
        __syncthreads();
        if (j == 0) { sd[gi] = best; si[gi] = bi; }
        __syncthreads();
        if (t == 0) {
            double b = sd[0]; int ib = si[0];
            #pragma unroll
            for (int q = 1; q < 16; ++q)
                if (sd[q] < b || (sd[q] == b && si[q] < ib)) { b = sd[q]; ib = si[q]; }
            scand[e * 32 + chunk] = b;
            scani[e * 32 + chunk] = ib;
        }
    }
}

// ---------------- K4bc: fused finalize — mergeA (blocks 0..31) + pairB (32..287) ----------------
__global__ __launch_bounds__(128) void k_fix(
    const float* __restrict__ x, const float* __restrict__ Wl, const float* __restrict__ bl,
    const float* __restrict__ emb,
    const int* __restrict__ rcntA, const int* __restrict__ rlistA,
    const double* __restrict__ scand, const int* __restrict__ scani,
    const int* __restrict__ rcntB, const int* __restrict__ rlistB,
    int* __restrict__ idxws, float* __restrict__ out_idxf)
{
    const int t = threadIdx.x;
    if (blockIdx.x < 32) {
        if (t < 64) {
            int cnt = *rcntA; if (cnt > RCAPA) cnt = RCAPA;
            for (int e = blockIdx.x; e < cnt; e += 32) {
                double b = 1e300; int ib = 0x7fffffff;
                if (t < 32) { b = scand[e * 32 + t]; ib = scani[e * 32 + t]; }
                #pragma unroll
                for (int o = 16; o; o >>= 1) {
                    double ob = __shfl_down(b, o, 64);
                    int oi = __shfl_down(ib, o, 64);
                    if (ob < b || (ob == b && oi < ib)) { b = ob; ib = oi; }
                }
                if (t == 0) { int n = rlistA[e]; idxws[n] = ib; out_idxf[n] = (float)ib; }
            }
        }
        return;
    }
    __shared__ double xs[128];
    __shared__ double red[128];
    __shared__ double red2[128];
    int cnt = *rcntB; if (cnt > RCAP) cnt = RCAP;
    for (int e = (int)blockIdx.x - 32; e < cnt; e += 256) {
        const int4 v = ((const int4*)rlistB)[e];
        const int n = v.x, c1 = v.y, c2 = v.z;
        const int b = n >> 10, hw = n & 1023;
        __syncthreads();
        xs[t] = (double)x[(size_t)(b * 128 + t) * 1024 + hw];
        __syncthreads();
        double z0 = (double)bl[t], z1 = 0.0, z2 = 0.0, z3 = 0.0;
        const float* wr = &Wl[(size_t)t * 128];
        #pragma unroll 8
        for (int c = 0; c < 128; c += 4) {
            z0 = fma((double)wr[c + 0], xs[c + 0], z0);
            z1 = fma((double)wr[c + 1], xs[c + 1], z1);
            z2 = fma((double)wr[c + 2], xs[c + 2], z2);
            z3 = fma((double)wr[c + 3], xs[c + 3], z3);
        }
        double z = (z0 + z1) + (z2 + z3);
        double da = z - (double)emb[(size_t)c1 * 128 + t];
        double db = z - (double)emb[(size_t)c2 * 128 + t];
        red[t] = da * da; red2[t] = db * db;
        __syncthreads();
        for (int o = 64; o; o >>= 1) {
            if (t < o) { red[t] += red[t + o]; red2[t] += red2[t + o]; }
            __syncthreads();
        }
        if (t == 0) {
            double d1v = red[0], d2v = red2[0];
            int win = (d2v < d1v || (d2v == d1v && c2 < c1)) ? c2 : c1;
            idxws[n] = win;
            out_idxf[n] = (float)win;
        }
        __syncthreads();
    }
}

// ---------------- K5: gather + transpose + histogram ----------------
__global__ __launch_bounds__(256) void k_out(
    const float* __restrict__ emb, const int* __restrict__ idxws,
    float* __restrict__ outp /* d_out + 1 */, float* __restrict__ counts)
{
    const int t = threadIdx.x;
    const int b  = blockIdx.x >> 4;          // 32 batches
    const int h2 = blockIdx.x & 15;          // 16 groups of 64 pixels
    const int pix = t & 63;
    const int cq  = t >> 6;                  // channel quarter (one per wave)
    const int n = b * 1024 + h2 * 64 + pix;
    const int id = idxws[n];
    if (cq == 0) atomicAdd(&counts[id], 1.0f);
    const float4* ep = (const float4*)&emb[(size_t)id * 128 + cq * 32];
    float* ob = outp + (size_t)b * 131072 + (size_t)cq * 32768 + h2 * 64 + pix;
    #pragma unroll
    for (int c4 = 0; c4 < 8; ++c4) {
        float4 v = ep[c4];
        __builtin_nontemporal_store(v.x, &ob[(c4 * 4 + 0) * 1024]);
        __builtin_nontemporal_store(v.y, &ob[(c4 * 4 + 1) * 1024]);
        __builtin_nontemporal_store(v.z, &ob[(c4 * 4 + 2) * 1024]);
        __builtin_nontemporal_store(v.w, &ob[(c4 * 4 + 3) * 1024]);
    }
}

// ---------------- K6: finalize loss + perplexity ----------------
__global__ __launch_bounds__(256) void k_final(
    const float* __restrict__ counts, const float* __restrict__ losssum, float* __restrict__ d_out)
{
    const int t = threadIdx.x;
    float ent = 0.f;
    for (int k = t; k < KCB; k += 256) {
        float p = counts[k] * (1.0f / 32768.0f);
        ent -= p * logf(p + 1e-10f);
    }
    #pragma unroll
    for (int o = 32; o; o >>= 1) ent += __shfl_down(ent, o, 64);
    __shared__ float wred[4];
    if ((t & 63) == 0) wred[t >> 6] = ent;
    __syncthreads();
    if (t == 0) {
        float e = wred[0] + wred[1] + wred[2] + wred[3];
        d_out[0] = 1.25f * (*losssum) * (1.0f / 4194304.0f);
        d_out[OUT_OFF_PERP] = expf(e);
    }
}

extern "C" void kernel_launch(void* const* d_in, const int* in_sizes, int n_in,
                              void* d_out, int out_size, void* d_ws, size_t ws_size,
                              hipStream_t stream) {
    (void)in_sizes; (void)n_in; (void)out_size; (void)ws_size;
    const float* x   = (const float*)d_in[0];
    const float* Wl  = (const float*)d_in[1];
    const float* bl  = (const float*)d_in[2];
    const float* emb = (const float*)d_in[3];
    float* out = (float*)d_out;
    char*  ws  = (char*)d_ws;

    _Float16* embFh = (_Float16*)(ws + WS_EMBFH);
    float* zws     = (float*)(ws + WS_ZWS);
    int*   idxws   = (int*)  (ws + WS_IDX);
    int*   rlistA  = (int*)  (ws + WS_RLISTA);
    int*   rlistB  = (int*)  (ws + WS_RLISTB);
    double* scand  = (double*)(ws + WS_SCAND);
    int*   scani   = (int*)  (ws + WS_SCANI);
    float* counts  = (float*)(ws + WS_COUNTS);
    float* losssum = (float*)(ws + WS_LOSS);
    int*   rcntA   = (int*)  (ws + WS_RCNTA);
    int*   rcntB   = (int*)  (ws + WS_RCNTB);
    int*   zerobuf = (int*)  (ws + WS_ZERO_OFF);

    k_prep2<<<KCB / 4, 256, 0, stream>>>(emb, embFh, zerobuf);
    k_main<<<NPIX / 64, 256, 0, stream>>>(x, Wl, bl, embFh, emb, zws, idxws,
                                          out + OUT_OFF_IDX, losssum,
                                          rlistA, rcntA, rlistB, rcntB);
    k_scanp<<<2048, 256, 0, stream>>>(zws, emb, rcntA, rlistA, scand, scani);
    k_fix<<<288, 128, 0, stream>>>(x, Wl, bl, emb, rcntA, rlistA, scand, scani,
                                   rcntB, rlistB, idxws, out + OUT_OFF_IDX);
    k_out<<<512, 256, 0, stream>>>(emb, idxws, out + OUT_OFF_OUT, counts);
    k_final<<<1, 256, 0, stream>>>(counts, losssum, out);
}

// Round 10
// 274.974 us; speedup vs baseline: 1.0325x; 1.0325x over previous
//
#include <hip/hip_runtime.h>
#include <hip/hip_bf16.h>
#include <float.h>

// Problem constants
#define NPIX   32768      // B*H*W
#define CDIM   128
#define KCB    8192
#define EPS_STOP 0.30f    // mask quant (0.031) + f16-dot error bound
#define TAUF   0.012f     // exact fp32 gap guard -> fp64 arbitration
#define RCAP   8192
#define RCAPA  2048

typedef _Float16 f16x8 __attribute__((ext_vector_type(8)));
typedef float    f32x16 __attribute__((ext_vector_type(16)));

// ws layout (bytes)
#define WS_EMBFH   0           // 2,359,296
#define WS_E2      2359296     // 32,768 (unused now)
#define WS_ZWS     2392064     // 16,777,216
#define WS_CAND    19169280    // 1,048,576
#define WS_IDX     20217856    // 131,072
#define WS_RLISTA  20348928    // 32,768 (cap 2048 used)
#define WS_RLISTB  20381696    // 131,072 (8192 * int4)
#define WS_SCAND   20512768    // 524,288 (2048*32 double)
#define WS_SCANI   21037056    // 262,144 (2048*32 int)
#define WS_COUNTS  21299200    // 32,768
#define WS_LOSS    21331968    // 4
#define WS_RCNTA   21331972    // 4
#define WS_RCNTB   21331976    // 4
#define WS_ZERO_OFF 21299200
#define WS_ZERO_LEN 32780      // 8195 ints

// d_out layout (f32): [0]=loss, [1..4194304]=out BCHW, [4194305]=perplexity, [4194306..]=idx
#define OUT_OFF_OUT  1
#define OUT_OFF_PERP 4194305
#define OUT_OFF_IDX  4194306

__device__ __forceinline__ float min3f(float a, float b, float c) {
    return fminf(fminf(a, b), c);   // -> v_min3_f32
}

__device__ __forceinline__ void ins6(float f, float v[6]) {
    float a = fmaxf(v[0], f); v[0] = fminf(v[0], f);
    float b = fmaxf(v[1], a); v[1] = fminf(v[1], a);
    a = fmaxf(v[2], b); v[2] = fminf(v[2], b);
    b = fmaxf(v[3], a); v[3] = fminf(v[3], a);
    a = fmaxf(v[4], b); v[4] = fminf(v[4], b);
    v[5] = fminf(v[5], a);
}

__device__ __forceinline__ float packmin(float m, uint32_t id) {
    return __uint_as_float((__float_as_uint(m) & 0xFFFFFE00u) | id);
}

// ---------------- K01: fused e2 + fragment prep + workspace zeroing ----------------
// One wave per codebook row m: lane l loads ch {2l,2l+1} (coalesced), e2 via the
// SAME shfl_down reduce as the old k_e2 (bit-identical); row staged in LDS; lanes
// 0..17 emit the 18 f16x8 fragments (-2*emb, e2+512 hi/lo fold, zero pad).
// Blocks 0..8 additionally zero the counts/loss/rcnt region (replaces memset).
__global__ __launch_bounds__(256) void k_prep2(const float* __restrict__ emb,
                                               _Float16* __restrict__ embFh,
                                               int* __restrict__ zerobuf) {
    const int t = threadIdx.x, w = t >> 6, l = t & 63;
    if (blockIdx.x < 9) {
        int idx0 = blockIdx.x * 1024 + t * 4;
        #pragma unroll
        for (int k = 0; k < 4; ++k)
            if (idx0 + k < 8195) zerobuf[idx0 + k] = 0;
    }
    __shared__ float rs[4][128];
    const int m = blockIdx.x * 4 + w;
    const float2 v = *(const float2*)&emb[(size_t)m * 128 + l * 2];
    rs[w][l * 2] = v.x; rs[w][l * 2 + 1] = v.y;
    float s = v.x * v.x + v.y * v.y;
    #pragma unroll
    for (int o = 32; o; o >>= 1) s += __shfl_down(s, o, 64);
    const float e2v = __shfl(s, 0, 64);

    f16x8 hv;
    #pragma unroll
    for (int j = 0; j < 8; ++j) hv[j] = (_Float16)0.0f;
    if (l < 16) {
        const float* rp = &rs[w][l * 8];
        #pragma unroll
        for (int j = 0; j < 8; ++j) hv[j] = (_Float16)(-2.0f * rp[j]);
    } else if (l == 16) {
        float vv = e2v + 512.0f;
        _Float16 eh = (_Float16)vv;
        hv[0] = eh;
        hv[1] = (_Float16)(vv - (float)eh);
    }
    if (l < 18) {
        const int s_ = l >> 1, h_ = l & 1;   // l<16: ch base = l*8 matches rp
        size_t base = (((size_t)(m >> 5) * 9 + s_) * 64 + (m & 31) + h_ * 32) * 8;
        *(f16x8*)&embFh[base] = hv;
    }
}

// ---------------- K2: fused linear + MFMA + packed group-min top-6 ----------------
// r3 structure (proven best): software-pipelined reduction — each tile's tail
// (tree16+ins6) is deferred until AFTER the next tile's 18-MFMA burst has issued.
// Ping-pong acc sets (e0/e1 vs o0/o1), named regs only.
__global__ __launch_bounds__(256, 2) void k_main(
    const float* __restrict__ x, const float* __restrict__ Wl, const float* __restrict__ bl,
    const _Float16* __restrict__ embFh,
    float* __restrict__ zws, float4* __restrict__ cand)
{
    __shared__ __align__(16) float As[64 * 132];   // z [p][c], pitch 132
    __shared__ __align__(16) float Xs[64 * 66];    // x staging / merge scratch
    __shared__ float z2p[256];                      // z^2 partials [p][ig]

    const int t  = threadIdx.x;
    const int n0 = blockIdx.x * 64;
    const int b  = n0 >> 10;
    const int hw0 = n0 & 1023;

    // ===== Phase 1: z for 64 pixels =====
    {
        const int p = t & 63, ig = t >> 6;
        float accz[32];
        const float4* bl4 = (const float4*)(bl + ig * 32);
        #pragma unroll
        for (int q = 0; q < 8; ++q) {
            float4 v = bl4[q];
            accz[4*q+0] = v.x; accz[4*q+1] = v.y; accz[4*q+2] = v.z; accz[4*q+3] = v.w;
        }
        for (int hf = 0; hf < 2; ++hf) {
            __syncthreads();
            for (int r = 0; r < 16; ++r) {
                int lin = r * 256 + t;
                int cc = lin >> 6, pp = lin & 63;
                Xs[cc * 66 + pp] = x[(size_t)(b * 128 + hf * 64 + cc) * 1024 + hw0 + pp];
            }
            __syncthreads();
            for (int cc4 = 0; cc4 < 16; ++cc4) {
                float xv0 = Xs[(cc4*4+0) * 66 + p];
                float xv1 = Xs[(cc4*4+1) * 66 + p];
                float xv2 = Xs[(cc4*4+2) * 66 + p];
                float xv3 = Xs[(cc4*4+3) * 66 + p];
                #pragma unroll
                for (int ii = 0; ii < 32; ++ii) {
                    const float4 w4 = *(const float4*)&Wl[(size_t)(ig*32+ii) * 128 + hf*64 + cc4*4];
                    float a = accz[ii];
                    a = fmaf(w4.x, xv0, a);
                    a = fmaf(w4.y, xv1, a);
                    a = fmaf(w4.z, xv2, a);
                    a = fmaf(w4.w, xv3, a);
                    accz[ii] = a;
                }
            }
        }
        float ssq = 0.f;
        float4* ao = (float4*)&As[p * 132 + ig * 32];
        float4* zo = (float4*)(zws + (size_t)(n0 + p) * 128 + ig * 32);
        #pragma unroll
        for (int q = 0; q < 8; ++q) {
            float4 v = make_float4(accz[4*q+0], accz[4*q+1], accz[4*q+2], accz[4*q+3]);
            ao[q] = v;
            zo[q] = v;
            ssq = fmaf(v.x, v.x, fmaf(v.y, v.y, fmaf(v.z, v.z, fmaf(v.w, v.w, ssq))));
        }
        z2p[p * 4 + ig] = ssq;
    }
    __syncthreads();

    // ===== Phase 2: B fragments (z f16) + constant fold step =====
    const int l = t & 63, w = t >> 6;
    const int half = l >> 5, pcol = l & 31;
    f16x8 B0[9], B1[9];
    #pragma unroll
    for (int nt = 0; nt < 2; ++nt) {
        int p = nt * 32 + pcol;
        #pragma unroll
        for (int s = 0; s < 8; ++s) {
            const float* zp = &As[p * 132 + s * 16 + half * 8];
            float4 v0 = *(const float4*)zp;
            float4 v1 = *(const float4*)(zp + 4);
            float vals[8] = {v0.x, v0.y, v0.z, v0.w, v1.x, v1.y, v1.z, v1.w};
            f16x8 hh;
            #pragma unroll
            for (int j2 = 0; j2 < 8; ++j2) hh[j2] = (_Float16)vals[j2];
            if (nt == 0) B0[s] = hh; else B1[s] = hh;
        }
    }
    {
        f16x8 b8;
        #pragma unroll
        for (int j2 = 0; j2 < 8; ++j2) b8[j2] = (_Float16)0.0f;
        if (half == 0) { b8[0] = (_Float16)1.0f; b8[1] = (_Float16)1.0f; }
        B0[8] = b8; B1[8] = b8;
    }

    // ===== Phase 3: K-loop, deferred-tail pipeline =====
    auto tree16 = [](const f32x16& v) -> float {
        float a = min3f(v[0], v[1], v[2]);
        float bb = min3f(v[3], v[4], v[5]);
        float c = min3f(v[6], v[7], v[8]);
        float d = min3f(v[9], v[10], v[11]);
        float e = min3f(v[12], v[13], v[14]);
        float f = min3f(a, bb, c);
        float g = min3f(d, e, v[15]);
        return fminf(f, g);
    };

    float gv[6] = {3e38f, 3e38f, 3e38f, 3e38f, 3e38f, 3e38f};   // tile0: px = pcol
    float hv[6] = {3e38f, 3e38f, 3e38f, 3e38f, 3e38f, 3e38f};   // tile1: px = 32+pcol
    const f16x8* Ahp = (const f16x8*)embFh;
    f16x8 aE[9], aO[9];
    {
        const f16x8* P = Ahp + (size_t)w * 576 + l;
        #pragma unroll
        for (int s = 0; s < 9; ++s) aE[s] = P[s * 64];
    }
    {
        const f16x8* P = Ahp + (size_t)(w + 4) * 576 + l;
        #pragma unroll
        for (int s = 0; s < 9; ++s) aO[s] = P[s * 64];
    }

    f32x16 e0, e1, o0, o1;
    uint32_t idv = (uint32_t)((w << 1) | half);

    // prologue: burst even tile w
    e0 = {}; e1 = {};
    #pragma unroll
    for (int s = 0; s < 9; ++s) {
        e0 = __builtin_amdgcn_mfma_f32_32x32x16_f16(aE[s], B0[s], e0, 0, 0, 0);
        e1 = __builtin_amdgcn_mfma_f32_32x32x16_f16(aE[s], B1[s], e1, 0, 0, 0);
    }

    for (int it = 0; it < 31; ++it) {
        const int g = w + it * 8;
        {   // refill aE <- tile g+8 (consumed by burstE at end of this iteration)
            const f16x8* P = Ahp + (size_t)(g + 8) * 576 + l;
            #pragma unroll
            for (int s = 0; s < 9; ++s) aE[s] = P[s * 64];
        }
        // burst odd tile g+4
        o0 = {}; o1 = {};
        #pragma unroll
        for (int s = 0; s < 9; ++s) {
            o0 = __builtin_amdgcn_mfma_f32_32x32x16_f16(aO[s], B0[s], o0, 0, 0, 0);
            o1 = __builtin_amdgcn_mfma_f32_32x32x16_f16(aO[s], B1[s], o1, 0, 0, 0);
        }
        // deferred tail: even tile g (burst issued one burst ago)
        {
            float m0 = tree16(e0), m1 = tree16(e1);
            ins6(packmin(m0, idv), gv);
            ins6(packmin(m1, idv), hv);
        }
        {   // refill aO <- tile g+12 (consumed by burstO next iteration / epilogue)
            const f16x8* P = Ahp + (size_t)(g + 12) * 576 + l;
            #pragma unroll
            for (int s = 0; s < 9; ++s) aO[s] = P[s * 64];
        }
        // burst even tile g+8
        e0 = {}; e1 = {};
        #pragma unroll
        for (int s = 0; s < 9; ++s) {
            e0 = __builtin_amdgcn_mfma_f32_32x32x16_f16(aE[s], B0[s], e0, 0, 0, 0);
            e1 = __builtin_amdgcn_mfma_f32_32x32x16_f16(aE[s], B1[s], e1, 0, 0, 0);
        }
        // deferred tail: odd tile g+4
        {
            float m0 = tree16(o0), m1 = tree16(o1);
            ins6(packmin(m0, idv + 8u), gv);
            ins6(packmin(m1, idv + 8u), hv);
        }
        idv += 16u;
    }
    // epilogue: last odd tile w+252 (aO loaded at it=30), then both remaining tails
    o0 = {}; o1 = {};
    #pragma unroll
    for (int s = 0; s < 9; ++s) {
        o0 = __builtin_amdgcn_mfma_f32_32x32x16_f16(aO[s], B0[s], o0, 0, 0, 0);
        o1 = __builtin_amdgcn_mfma_f32_32x32x16_f16(aO[s], B1[s], o1, 0, 0, 0);
    }
    {   // tail even tile w+248
        float m0 = tree16(e0), m1 = tree16(e1);
        ins6(packmin(m0, idv), gv);
        ins6(packmin(m1, idv), hv);
    }
    {   // tail odd tile w+252
        float m0 = tree16(o0), m1 = tree16(o1);
        ins6(packmin(m0, idv + 8u), gv);
        ins6(packmin(m1, idv + 8u), hv);
    }

    // ===== Phase 4: cross-wave merge per pixel, write cand (6 groups + z2) =====
    __syncthreads();
    float* Ms = Xs;   // [64 px][8 slots][6]
    const int slot = (w << 1) | half;
    #pragma unroll
    for (int q = 0; q < 6; ++q) {
        Ms[(pcol * 8 + slot) * 6 + q] = gv[q];
        Ms[((32 + pcol) * 8 + slot) * 6 + q] = hv[q];
    }
    __syncthreads();
    if (t < 64) {
        float v6[6] = {3e38f, 3e38f, 3e38f, 3e38f, 3e38f, 3e38f};
        #pragma unroll
        for (int s = 0; s < 48; ++s) ins6(Ms[t * 48 + s], v6);
        float z2 = z2p[t*4+0] + z2p[t*4+1] + z2p[t*4+2] + z2p[t*4+3];
        cand[(size_t)(n0 + t) * 2 + 0] = make_float4(v6[0], v6[1], v6[2], v6[3]);
        cand[(size_t)(n0 + t) * 2 + 1] = make_float4(v6[4], v6[5], z2, 0.f);
    }
}

// ---------------- K3: early-exit exact fp32 over candidate groups ----------------
// Two partial-sum chains (s0/s1) halve the dependent-FMA depth per code.
__global__ __launch_bounds__(256) void k_rec(
    const float* __restrict__ zws, const float* __restrict__ emb,
    const float4* __restrict__ cand, int* __restrict__ idxws,
    float* __restrict__ out_idxf, float* __restrict__ losssum,
    int* __restrict__ rlistA, int* __restrict__ rcntA,
    int* __restrict__ rlistB, int* __restrict__ rcntB)
{
    __shared__ float lred[16];
    const int t = threadIdx.x;
    const int pl = t >> 4, j = t & 15;
    const int n = blockIdx.x * 16 + pl;

    const float4 za = *(const float4*)&zws[(size_t)n * 128 + j * 8];
    const float4 zb = *(const float4*)&zws[(size_t)n * 128 + j * 8 + 4];
    const float4 c0 = cand[(size_t)n * 2 + 0];
    const float4 c1 = cand[(size_t)n * 2 + 1];
    const float pv[6] = {c0.x, c0.y, c0.z, c0.w, c1.x, c1.y};
    const float pbase = c1.z - 512.0f;   // d = packed + pbase

    float d1 = 3e38f, d2 = 3e38f; int i1 = 0x7fffffff, i2 = 0x7fffffff;
    bool safe = false;
    float lastgmin = 0.f;
    for (int q = 0; q < 6; ++q) {
        uint32_t bits = __float_as_uint(pv[q]);
        float gmin = __uint_as_float(bits & 0xFFFFFE00u);
        lastgmin = gmin;
        if (gmin >= d1 - pbase + EPS_STOP) { safe = true; break; }
        const int mbase = (int)((bits >> 1) & 255u) * 32 + (int)((bits & 1u) << 2); // tile*32 + half*4
        #pragma unroll
        for (int c = 0; c < 16; ++c) {
            int m = mbase + (c & 3) + 8 * (c >> 2);
            const float4 ea = *(const float4*)&emb[(size_t)m * 128 + j * 8];
            const float4 eb = *(const float4*)&emb[(size_t)m * 128 + j * 8 + 4];
            float da0 = za.x - ea.x, da1 = za.y - ea.y, da2 = za.z - ea.z, da3 = za.w - ea.w;
            float db0 = zb.x - eb.x, db1 = zb.y - eb.y, db2 = zb.z - eb.z, db3 = zb.w - eb.w;
            float s0 = da0*da0; s0 = fmaf(da1, da1, s0); s0 = fmaf(da2, da2, s0); s0 = fmaf(da3, da3, s0);
            float s1 = db0*db0; s1 = fmaf(db1, db1, s1); s1 = fmaf(db2, db2, s1); s1 = fmaf(db3, db3, s1);
            float s = s0 + s1;
            s += __shfl_xor(s, 1, 16);
            s += __shfl_xor(s, 2, 16);
            s += __shfl_xor(s, 4, 16);
            s += __shfl_xor(s, 8, 16);
            if (s < d1 || (s == d1 && m < i1)) { d2 = d1; i2 = i1; d1 = s; i1 = m; }
            else if (s < d2) { d2 = s; i2 = m; }
        }
    }
    if (!safe && lastgmin >= d1 - pbase + EPS_STOP) safe = true;  // post-check vs pv[5]

    if (j == 0) {
        idxws[n] = i1;
        out_idxf[n] = (float)i1;
        if (!safe) {
            int s = atomicAdd(rcntA, 1);
            if (s < RCAPA) rlistA[s] = n;
        } else if ((d2 - d1) < TAUF) {
            int s = atomicAdd(rcntB, 1);
            if (s < RCAP) { int4 v4 = make_int4(n, i1, i2, 0); ((int4*)rlistB)[s] = v4; }
        }
        lred[pl] = d1;
    }
    __syncthreads();
    if (t == 0) {
        float ls = 0.f;
        #pragma unroll
        for (int q = 0; q < 16; ++q) ls += lred[q];
        atomicAdd(losssum, ls);
    }
}

// ---------------- K4a: parallel full scan for !safe pixels ----------------
// Two fp64 partial sums halve the dependent chain per code.
__global__ __launch_bounds__(256) void k_scanp(
    const float* __restrict__ zws, const float* __restrict__ emb,
    const int* __restrict__ rcntA, const int* __restrict__ rlistA,
    double* __restrict__ scand, int* __restrict__ scani)
{
    int cnt = *rcntA; if (cnt > RCAPA) cnt = RCAPA;
    const int t = threadIdx.x;
    const int chunk = blockIdx.x & 31;
    const int gi = t >> 4, j = t & 15;
    __shared__ double sd[16];
    __shared__ int si[16];
    for (int e = blockIdx.x >> 5; e < cnt; e += 64) {
        const int n = rlistA[e];
        const float4 za = *(const float4*)&zws[(size_t)n * 128 + j * 8];
        const float4 zb = *(const float4*)&zws[(size_t)n * 128 + j * 8 + 4];
        double best = 1e300; int bi = 0x7fffffff;
        const int kbase = chunk * 256 + gi * 16;
        for (int c = 0; c < 16; ++c) {
            const int m = kbase + c;
            const float4 ea = *(const float4*)&emb[(size_t)m * 128 + j * 8];
            const float4 eb = *(const float4*)&emb[(size_t)m * 128 + j * 8 + 4];
            double sa = 0.0, sb = 0.0, d;
            d = (double)za.x - (double)ea.x; sa += d * d;
            d = (double)za.y - (double)ea.y; sa += d * d;
            d = (double)za.z - (double)ea.z; sa += d * d;
            d = (double)za.w - (double)ea.w; sa += d * d;
            d = (double)zb.x - (double)eb.x; sb += d * d;
            d = (double)zb.y - (double)eb.y; sb += d * d;
            d = (double)zb.z - (double)eb.z; sb += d * d;
            d = (double)zb.w - (double)eb.w; sb += d * d;
            double s = sa + sb;
            s += __shfl_xor(s, 1, 16);
            s += __shfl_xor(s, 2, 16);
            s += __shfl_xor(s, 4, 16);
            s += __shfl_xor(s, 8, 16);
            if (s < best) { best = s; bi = m; }   // m strictly increasing -> first-index
        }
        __syncthreads();
        if (j == 0) { sd[gi] = best; si[gi] = bi; }
        __syncthreads();
        if (t == 0) {
            double b = sd[0]; int ib = si[0];
            #pragma unroll
            for (int q = 1; q < 16; ++q)
                if (sd[q] < b || (sd[q] == b && si[q] < ib)) { b = sd[q]; ib = si[q]; }
            scand[e * 32 + chunk] = b;
            scani[e * 32 + chunk] = ib;
        }
    }
}

// ---------------- K4bc: fused finalize — blocks [0,32) merge chunk results (!safe),
// blocks [32,288) fp64 pair arbitration (near-tie). Pixel sets disjoint by construction.
// pairB: 4-way ILP fp64 dot + fused dual reduction (7 syncs, was 14).
__global__ __launch_bounds__(128) void k_fix(
    const float* __restrict__ x, const float* __restrict__ Wl, const float* __restrict__ bl,
    const float* __restrict__ emb,
    const int* __restrict__ rcntA, const int* __restrict__ rlistA,
    const double* __restrict__ scand, const int* __restrict__ scani,
    const int* __restrict__ rcntB, const int* __restrict__ rlistB,
    int* __restrict__ idxws, float* __restrict__ out_idxf)
{
    const int t = threadIdx.x;
    if (blockIdx.x < 32) {
        // ---- mergeA: 32 blocks, first wave only ----
        if (t < 64) {
            int cnt = *rcntA; if (cnt > RCAPA) cnt = RCAPA;
            for (int e = blockIdx.x; e < cnt; e += 32) {
                double b = 1e300; int ib = 0x7fffffff;
                if (t < 32) { b = scand[e * 32 + t]; ib = scani[e * 32 + t]; }
                #pragma unroll
                for (int o = 16; o; o >>= 1) {
                    double ob = __shfl_down(b, o, 64);
                    int oi = __shfl_down(ib, o, 64);
                    if (ob < b || (ob == b && oi < ib)) { b = ob; ib = oi; }
                }
                if (t == 0) { int n = rlistA[e]; idxws[n] = ib; out_idxf[n] = (float)ib; }
            }
        }
        return;
    }
    // ---- pairB: 256 blocks ----
    __shared__ double xs[128];
    __shared__ double red[128];
    __shared__ double red2[128];
    int cnt = *rcntB; if (cnt > RCAP) cnt = RCAP;
    for (int e = (int)blockIdx.x - 32; e < cnt; e += 256) {
        const int4 v = ((const int4*)rlistB)[e];
        const int n = v.x, c1 = v.y, c2 = v.z;
        const int b = n >> 10, hw = n & 1023;
        __syncthreads();
        xs[t] = (double)x[(size_t)(b * 128 + t) * 1024 + hw];
        __syncthreads();
        double z0 = (double)bl[t], z1 = 0.0, z2 = 0.0, z3 = 0.0;
        const float* wr = &Wl[(size_t)t * 128];
        #pragma unroll 8
        for (int c = 0; c < 128; c += 4) {
            z0 = fma((double)wr[c + 0], xs[c + 0], z0);
            z1 = fma((double)wr[c + 1], xs[c + 1], z1);
            z2 = fma((double)wr[c + 2], xs[c + 2], z2);
            z3 = fma((double)wr[c + 3], xs[c + 3], z3);
        }
        double z = (z0 + z1) + (z2 + z3);
        double da = z - (double)emb[(size_t)c1 * 128 + t];
        double db = z - (double)emb[(size_t)c2 * 128 + t];
        red[t] = da * da; red2[t] = db * db;
        __syncthreads();
        for (int o = 64; o; o >>= 1) {
            if (t < o) { red[t] += red[t + o]; red2[t] += red2[t + o]; }
            __syncthreads();
        }
        if (t == 0) {
            double d1v = red[0], d2v = red2[0];
            int win = (d2v < d1v || (d2v == d1v && c2 < c1)) ? c2 : c1;
            idxws[n] = win;
            out_idxf[n] = (float)win;
        }
        __syncthreads();
    }
}

// ---------------- K5: gather + transpose + histogram ----------------
// 512 blocks x 256 thr: each block = 64 pixels; each wave owns one channel-quarter.
__global__ __launch_bounds__(256) void k_out(
    const float* __restrict__ emb, const int* __restrict__ idxws,
    float* __restrict__ outp /* d_out + 1 */, float* __restrict__ counts)
{
    const int t = threadIdx.x;
    const int b  = blockIdx.x >> 4;          // 32 batches
    const int h2 = blockIdx.x & 15;          // 16 groups of 64 pixels
    const int pix = t & 63;
    const int cq  = t >> 6;                  // channel quarter (one per wave)
    const int n = b * 1024 + h2 * 64 + pix;
    const int id = idxws[n];
    if (cq == 0) atomicAdd(&counts[id], 1.0f);
    const float4* ep = (const float4*)&emb[(size_t)id * 128 + cq * 32];
    float* ob = outp + (size_t)b * 131072 + (size_t)cq * 32768 + h2 * 64 + pix;
    #pragma unroll
    for (int c4 = 0; c4 < 8; ++c4) {
        float4 v = ep[c4];
        __builtin_nontemporal_store(v.x, &ob[(c4 * 4 + 0) * 1024]);
        __builtin_nontemporal_store(v.y, &ob[(c4 * 4 + 1) * 1024]);
        __builtin_nontemporal_store(v.z, &ob[(c4 * 4 + 2) * 1024]);
        __builtin_nontemporal_store(v.w, &ob[(c4 * 4 + 3) * 1024]);
    }
}

// ---------------- K6: finalize loss + perplexity ----------------
__global__ __launch_bounds__(256) void k_final(
    const float* __restrict__ counts, const float* __restrict__ losssum, float* __restrict__ d_out)
{
    const int t = threadIdx.x;
    float ent = 0.f;
    for (int k = t; k < KCB; k += 256) {
        float p = counts[k] * (1.0f / 32768.0f);
        ent -= p * logf(p + 1e-10f);
    }
    #pragma unroll
    for (int o = 32; o; o >>= 1) ent += __shfl_down(ent, o, 64);
    __shared__ float wred[4];
    if ((t & 63) == 0) wred[t >> 6] = ent;
    __syncthreads();
    if (t == 0) {
        float e = wred[0] + wred[1] + wred[2] + wred[3];
        d_out[0] = 1.25f * (*losssum) * (1.0f / 4194304.0f);
        d_out[OUT_OFF_PERP] = expf(e);
    }
}

extern "C" void kernel_launch(void* const* d_in, const int* in_sizes, int n_in,
                              void* d_out, int out_size, void* d_ws, size_t ws_size,
                              hipStream_t stream) {
    (void)in_sizes; (void)n_in; (void)out_size; (void)ws_size;
    const float* x   = (const float*)d_in[0];
    const float* Wl  = (const float*)d_in[1];
    const float* bl  = (const float*)d_in[2];
    const float* emb = (const float*)d_in[3];
    float* out = (float*)d_out;
    char*  ws  = (char*)d_ws;

    _Float16* embFh = (_Float16*)(ws + WS_EMBFH);
    float* zws     = (float*)(ws + WS_ZWS);
    float4* cand   = (float4*)(ws + WS_CAND);
    int*   idxws   = (int*)  (ws + WS_IDX);
    int*   rlistA  = (int*)  (ws + WS_RLISTA);
    int*   rlistB  = (int*)  (ws + WS_RLISTB);
    double* scand  = (double*)(ws + WS_SCAND);
    int*   scani   = (int*)  (ws + WS_SCANI);
    float* counts  = (float*)(ws + WS_COUNTS);
    float* losssum = (float*)(ws + WS_LOSS);
    int*   rcntA   = (int*)  (ws + WS_RCNTA);
    int*   rcntB   = (int*)  (ws + WS_RCNTB);
    int*   zerobuf = (int*)  (ws + WS_ZERO_OFF);

    k_prep2<<<KCB / 4, 256, 0, stream>>>(emb, embFh, zerobuf);
    k_main<<<NPIX / 64, 256, 0, stream>>>(x, Wl, bl, embFh, zws, cand);
    k_rec<<<NPIX / 16, 256, 0, stream>>>(zws, emb, cand, idxws, out + OUT_OFF_IDX,
                                         losssum, rlistA, rcntA, rlistB, rcntB);
    k_scanp<<<2048, 256, 0, stream>>>(zws, emb, rcntA, rlistA, scand, scani);
    k_fix<<<288, 128, 0, stream>>>(x, Wl, bl, emb, rcntA, rlistA, scand, scani,
                                   rcntB, rlistB, idxws, out + OUT_OFF_IDX);
    k_out<<<512, 256, 0, stream>>>(emb, idxws, out + OUT_OFF_OUT, counts);
    k_final<<<1, 256, 0, stream>>>(counts, losssum, out);
}